// Round 1
// baseline (26.281 us; speedup 1.0000x reference)
//
#include <hip/hip_runtime.h>
#include <math.h>

// Problem constants (fixed by setup_inputs): h [8,4096,512] f32, patch_ids [8,4096] i32 sorted,
// P=1024, k=4. Output [8,1024,512] f32.
#define BS   8
#define SEQ  4096
#define DIM  512
#define NP   1024
#define KTOP 4
#define NEGINF_C (-1.0e9f)

// ---------------------------------------------------------------------------
// Kernel A: segment boundaries. starts[b*(NP+1)+p] = first token index t with
// ids[t] >= p (lower_bound). starts[b][NP] = SEQ. Exploits sortedness.
// ---------------------------------------------------------------------------
__global__ __launch_bounds__(256) void boundaries_kernel(const int* __restrict__ pid,
                                                         int* __restrict__ starts) {
    const int gt = blockIdx.x * 256 + threadIdx.x;   // [0, BS*SEQ)
    const int b  = gt / SEQ;
    const int t  = gt - b * SEQ;
    const int* ids = pid + b * SEQ;
    int* st = starts + b * (NP + 1);

    const int cur  = ids[t];
    const int prev = (t > 0) ? ids[t - 1] : -1;
    for (int p = prev + 1; p <= cur; ++p) st[p] = t;
    if (t == SEQ - 1) {
        for (int p = cur + 1; p <= NP; ++p) st[p] = SEQ;
    }
}

// ---------------------------------------------------------------------------
// Branchless distinct-insert into descending 4-list.
// Reference semantics: iteration takes the max and knocks out ALL ties, so the
// collected values are the distinct values in descending order.
// ---------------------------------------------------------------------------
__device__ __forceinline__ void ins4(float v, float& m0, float& m1, float& m2, float& m3) {
    const bool dup = (v == m0) | (v == m1) | (v == m2) | (v == m3);
    v = dup ? -INFINITY : v;   // -inf never displaces anything
    float a;
    a = fmaxf(m0, v); v = fminf(m0, v); m0 = a;
    a = fmaxf(m1, v); v = fminf(m1, v); m1 = a;
    a = fmaxf(m2, v); v = fminf(m2, v); m2 = a;
    m3 = fmaxf(m3, v);
}

// ---------------------------------------------------------------------------
// Kernel B: one block per (b, p). 256 threads x float2 = 512 dims.
// ---------------------------------------------------------------------------
__global__ __launch_bounds__(256) void topk_pool_kernel(const float* __restrict__ h,
                                                        const int* __restrict__ starts,
                                                        float* __restrict__ out) {
    const int bp = blockIdx.x;            // b*NP + p
    const int b  = bp >> 10;              // / NP
    const int p  = bp & (NP - 1);
    const int tid = threadIdx.x;

    const int* st   = starts + b * (NP + 1);
    const int start = st[p];
    const int end   = st[p + 1];
    const int cnt   = end - start;

    float2* outv = (float2*)(out + ((size_t)b * NP + p) * DIM);

    if (cnt == 0) {                       // empty patch -> all-zero row
        outv[tid] = make_float2(0.0f, 0.0f);
        return;
    }

    const float2* hb = (const float2*)(h + (size_t)b * SEQ * DIM);

    float x0 = -INFINITY, x1 = -INFINITY, x2 = -INFINITY, x3 = -INFINITY;
    float y0 = -INFINITY, y1 = -INFINITY, y2 = -INFINITY, y3 = -INFINITY;

    for (int t = start; t < end; ++t) {
        const float2 v = hb[(size_t)t * (DIM / 2) + tid];
        ins4(v.x, x0, x1, x2, x3);
        ins4(v.y, y0, y1, y2, y3);
    }

    const int n = (cnt < KTOP) ? cnt : KTOP;
    const float xs[4] = {x0, x1, x2, x3};
    const float ys[4] = {y0, y1, y2, y3};
    float sx = 0.0f, sy = 0.0f;
    #pragma unroll
    for (int i = 0; i < KTOP; ++i) {
        if (i < n) {
            // fewer than n distinct values -> reference averages NEG_INF pads
            sx += (xs[i] == -INFINITY) ? NEGINF_C : xs[i];
            sy += (ys[i] == -INFINITY) ? NEGINF_C : ys[i];
        }
    }
    const float nf = (float)n;
    outv[tid] = make_float2(sx / nf, sy / nf);
}

// ---------------------------------------------------------------------------
extern "C" void kernel_launch(void* const* d_in, const int* in_sizes, int n_in,
                              void* d_out, int out_size, void* d_ws, size_t ws_size,
                              hipStream_t stream) {
    const float* h   = (const float*)d_in[0];
    const int*   pid = (const int*)d_in[1];
    float*       out = (float*)d_out;
    int*         starts = (int*)d_ws;     // BS*(NP+1)*4 = 32.8 KB

    boundaries_kernel<<<dim3((BS * SEQ) / 256), dim3(256), 0, stream>>>(pid, starts);
    topk_pool_kernel<<<dim3(BS * NP), dim3(256), 0, stream>>>(h, starts, out);
}